// Round 3
// baseline (55.339 us; speedup 1.0000x reference)
//
#include <hip/hip_runtime.h>

// Problem constants (match reference)
#define PNX 432
#define PNY 496
#define PNC 64
#define PLANE (PNY * PNX)   // 214272 = 837*256, divisible by 1024

typedef float f32x4 __attribute__((ext_vector_type(4)));

// ---------------- map build ----------------

// Scatter pillar index p into map at its global cell. (map pre-set to -1
// via hipMemsetAsync 0xFF.)
__global__ void pp_scatter_map(const int4* __restrict__ coords,
                               int* __restrict__ map, int P) {
    int p = blockIdx.x * blockDim.x + threadIdx.x;
    if (p >= P) return;
    int4 c = coords[p];              // (b, z, y, x)
    int gidx = c.x * PLANE + c.y + c.z * PNX + c.w;
    map[gidx] = p;
}

// ---------------- gather ----------------
// Grid: (n4 blocks, 4). Each thread: 4 consecutive cells x 16 channels.
// Feature rows loaded as 16B chunks; 4x4 register transpose; nontemporal
// 16B stores (output is streamed, never re-read).
__global__ void pp_gather(const float* __restrict__ feat,
                          const int* __restrict__ map,
                          float* __restrict__ out, int n4) {
    int t = blockIdx.x * blockDim.x + threadIdx.x;   // cell4 index
    if (t >= n4) return;
    int cell0 = t * 4;
    int b = cell0 / PLANE;
    int spat = cell0 - b * PLANE;
    int cbase = blockIdx.y * (PNC / 4);              // 16 channels per y-slice

    int4 pm = *reinterpret_cast<const int4*>(map + cell0);
    const f32x4* fp0 = reinterpret_cast<const f32x4*>(feat + (long)pm.x * PNC + cbase);
    const f32x4* fp1 = reinterpret_cast<const f32x4*>(feat + (long)pm.y * PNC + cbase);
    const f32x4* fp2 = reinterpret_cast<const f32x4*>(feat + (long)pm.z * PNC + cbase);
    const f32x4* fp3 = reinterpret_cast<const f32x4*>(feat + (long)pm.w * PNC + cbase);

    float* outp = out + (size_t)b * PNC * PLANE + (size_t)cbase * PLANE + spat;
    const f32x4 z = {0.f, 0.f, 0.f, 0.f};

    #pragma unroll
    for (int g = 0; g < 4; ++g) {                    // 4 channels per group
        f32x4 r0 = (pm.x >= 0) ? fp0[g] : z;
        f32x4 r1 = (pm.y >= 0) ? fp1[g] : z;
        f32x4 r2 = (pm.z >= 0) ? fp2[g] : z;
        f32x4 r3 = (pm.w >= 0) ? fp3[g] : z;
        // transpose: output channel c holds (cell0..cell0+3)
        f32x4 o0 = {r0.x, r1.x, r2.x, r3.x};
        f32x4 o1 = {r0.y, r1.y, r2.y, r3.y};
        f32x4 o2 = {r0.z, r1.z, r2.z, r3.z};
        f32x4 o3 = {r0.w, r1.w, r2.w, r3.w};
        float* o = outp + (size_t)(g * 4) * PLANE;
        __builtin_nontemporal_store(o0, reinterpret_cast<f32x4*>(o));
        __builtin_nontemporal_store(o1, reinterpret_cast<f32x4*>(o + PLANE));
        __builtin_nontemporal_store(o2, reinterpret_cast<f32x4*>(o + 2 * PLANE));
        __builtin_nontemporal_store(o3, reinterpret_cast<f32x4*>(o + 3 * PLANE));
    }
}

// ---------------- fallback path (ws too small) ----------------

__global__ void pp_zero_out(f32x4* __restrict__ out4, size_t n4) {
    size_t t = (size_t)blockIdx.x * blockDim.x + threadIdx.x;
    size_t stride = (size_t)gridDim.x * blockDim.x;
    const f32x4 z = {0.f, 0.f, 0.f, 0.f};
    for (size_t i = t; i < n4; i += stride) out4[i] = z;
}

__global__ void pp_scatter_direct(const float* __restrict__ feat,
                                  const int4* __restrict__ coords,
                                  float* __restrict__ out, int P) {
    int t = blockIdx.x * blockDim.x + threadIdx.x;
    int p = t >> 6;
    int c = t & 63;
    if (p >= P) return;
    int4 co = coords[p];
    size_t oidx = ((size_t)(co.x * PNC + c)) * PLANE + co.y + co.z * PNX + co.w;
    out[oidx] = feat[p * PNC + c];
}

extern "C" void kernel_launch(void* const* d_in, const int* in_sizes, int n_in,
                              void* d_out, int out_size, void* d_ws, size_t ws_size,
                              hipStream_t stream) {
    const float* feat = (const float*)d_in[0];
    const int4* coords = (const int4*)d_in[1];
    float* out = (float*)d_out;

    const int P = in_sizes[0] / PNC;                 // 64000
    const int B = out_size / (PNC * PLANE);          // 4
    const int ncells = B * PLANE;                    // 857088
    const size_t mapBytes = (size_t)ncells * sizeof(int);

    if (ws_size >= mapBytes) {
        int* map = (int*)d_ws;
        int n4 = ncells / 4;                         // 214272
        // 1. map = -1 (0xFFFFFFFF) via the optimized rocclr fill
        (void)hipMemsetAsync(map, 0xFF, mapBytes, stream);
        // 2. scatter pillar ids into map
        pp_scatter_map<<<(P + 255) / 256, 256, 0, stream>>>(coords, map, P);
        // 3. gather: write every output element (coalesced nt float4)
        dim3 grid((n4 + 255) / 256, 4);
        pp_gather<<<grid, 256, 0, stream>>>(feat, map, out, n4);
    } else {
        // Fallback: zero-fill + direct scatter (correct but more HBM traffic)
        size_t n4 = (size_t)out_size / 4;
        pp_zero_out<<<2048, 256, 0, stream>>>((f32x4*)out, n4);
        int total = P * PNC;
        pp_scatter_direct<<<(total + 255) / 256, 256, 0, stream>>>(feat, coords, out, P);
    }
}